// Round 1
// baseline (136.496 us; speedup 1.0000x reference)
//
#include <hip/hip_runtime.h>
#include <hip/hip_bf16.h>

#define B_   32
#define L_   2048
#define DIN  384
#define DH   64
#define DOUT 64
#define NC   32      // chunks per sequence
#define CS   64      // chunk length
#define WN   192     // combined weight rows: [Bu_re | Bu_im | Du]

typedef __attribute__((ext_vector_type(8))) short short8;
typedef __attribute__((ext_vector_type(4))) float f32x4;

__device__ __forceinline__ float bf2f(short s) {
  union { unsigned u; float f; } cv;
  cv.u = ((unsigned)(unsigned short)s) << 16;
  return cv.f;
}
__device__ __forceinline__ short f2bf(float f) {
  union { float f; unsigned u; } cv; cv.f = f;
  unsigned r = cv.u + 0x7fffu + ((cv.u >> 16) & 1u);   // RNE, finite inputs
  return (short)(r >> 16);
}

// ---------------- K0: weights / lambda / Ct prep ----------------
__global__ void k0_prep(const float* __restrict__ nu_log, const float* __restrict__ theta_log,
                        const float* __restrict__ gamma_log,
                        const float* __restrict__ B_re, const float* __restrict__ B_im,
                        const float* __restrict__ C_re, const float* __restrict__ C_im,
                        const float* __restrict__ Dm,
                        short* __restrict__ W, float* __restrict__ lamtab,
                        float* __restrict__ Ct) {
  int tid = blockIdx.x * 256 + threadIdx.x;
  // W[n][k], n<64: B_re*gamma ; n<128: B_im*gamma ; else D
  for (int idx = tid; idx < WN * DIN; idx += gridDim.x * 256) {
    int n = idx / DIN, k = idx - n * DIN;
    float v;
    if (n < 64)       v = B_re[n * DIN + k] * expf(gamma_log[n]);
    else if (n < 128) v = B_im[(n - 64) * DIN + k] * expf(gamma_log[n - 64]);
    else              v = Dm[(n - 128) * DIN + k];
    W[idx] = f2bf(v);
  }
  // Ct[h][o] = C_re[o][h] ; Ct[4096 + h*64 + o] = -C_im[o][h]
  for (int idx = tid; idx < DH * DOUT; idx += gridDim.x * 256) {
    int h = idx / DOUT, o = idx - h * DOUT;
    Ct[idx] = C_re[o * DH + h];
    Ct[DH * DOUT + idx] = -C_im[o * DH + h];
  }
  if (blockIdx.x == 0 && threadIdx.x < 64) {
    int h = threadIdx.x;
    float nu = expf(nu_log[h]);
    float th = expf(theta_log[h]);
    float rr = expf(-nu);
    float lr = rr * cosf(th), li = rr * sinf(th);
    float ar = lr, ai = li;
    #pragma unroll
    for (int q = 0; q < 6; ++q) { float nr = ar * ar - ai * ai; ai = 2.f * ar * ai; ar = nr; }
    lamtab[h] = lr; lamtab[64 + h] = li;       // lambda
    lamtab[128 + h] = ar; lamtab[192 + h] = ai; // lambda^64
  }
}

// ---------------- K1: Z[65536][192] = X @ W^T (bf16 MFMA) ----------------
__global__ __launch_bounds__(256) void k1_gemm(const float* __restrict__ X,
                                               const short* __restrict__ W,
                                               short* __restrict__ Z) {
  const int wave = threadIdx.x >> 6, lane = threadIdx.x & 63;
  const int m0 = blockIdx.x * 64 + wave * 16;
  const int r = lane & 15, kq = lane >> 4;   // A row / k-quarter
  f32x4 acc[12];
  #pragma unroll
  for (int i = 0; i < 12; ++i) acc[i] = (f32x4){0.f, 0.f, 0.f, 0.f};
  const float* xp = X + (size_t)(m0 + r) * DIN + kq * 8;
  for (int ks = 0; ks < 12; ++ks) {
    f32x4 a0 = *(const f32x4*)(xp + ks * 32);
    f32x4 a1 = *(const f32x4*)(xp + ks * 32 + 4);
    short8 af;
    #pragma unroll
    for (int i = 0; i < 4; ++i) { af[i] = f2bf(a0[i]); af[4 + i] = f2bf(a1[i]); }
    #pragma unroll
    for (int nt = 0; nt < 12; ++nt) {
      short8 bf = *(const short8*)(W + (nt * 16 + r) * DIN + ks * 32 + kq * 8);
      acc[nt] = __builtin_amdgcn_mfma_f32_16x16x32_bf16(af, bf, acc[nt], 0, 0, 0);
    }
  }
  #pragma unroll
  for (int nt = 0; nt < 12; ++nt) {
    #pragma unroll
    for (int j = 0; j < 4; ++j) {
      int m = m0 + kq * 4 + j;              // D: row=(lane>>4)*4+j, col=lane&15
      Z[(size_t)m * WN + nt * 16 + r] = f2bf(acc[nt][j]);
    }
  }
}

// ---------------- K2: chunk end-states E = sum_t lam^{63-t} Bu[t] ----------------
__global__ __launch_bounds__(256) void k2_chunkE(const short* __restrict__ Z,
                                                 const float* __restrict__ lamtab,
                                                 float* __restrict__ E) {
  const int c = blockIdx.x, b = blockIdx.y;
  const int t = threadIdx.x, h = t & 63, g = t >> 6;
  const float lr = lamtab[h], li = lamtab[64 + h];
  float p16r = lr, p16i = li;
  #pragma unroll
  for (int q = 0; q < 4; ++q) { float nr = p16r * p16r - p16i * p16i; p16i = 2.f * p16r * p16i; p16r = nr; }
  float wr = 1.f, wi = 0.f;                 // lam^{16*(3-g)}
  for (int q = 0; q < 3 - g; ++q) { float nr = wr * p16r - wi * p16i; wi = wr * p16i + wi * p16r; wr = nr; }
  float er = 0.f, ei = 0.f;
  const short* base = Z + (size_t)(b * L_ + c * CS) * WN;
  for (int l = g * 16 + 15; l >= g * 16; --l) {
    float br = bf2f(base[l * WN + h]);
    float bi = bf2f(base[l * WN + 64 + h]);
    er += wr * br - wi * bi;
    ei += wr * bi + wi * br;
    float nr = wr * lr - wi * li; wi = wr * li + wi * lr; wr = nr;
  }
  __shared__ float red[4][2][64];
  red[g][0][h] = er; red[g][1][h] = ei;
  __syncthreads();
  if (t < 64) {
    float sr = red[0][0][t] + red[1][0][t] + red[2][0][t] + red[3][0][t];
    float si = red[0][1][t] + red[1][1][t] + red[2][1][t] + red[3][1][t];
    float* Ep = E + (size_t)(b * NC + c) * 128;
    Ep[t] = sr; Ep[64 + t] = si;
  }
}

// ---------------- K4: carry + local scan + C-proj + Du + chunk max ----------------
__global__ __launch_bounds__(256) void k4_scanproj(const short* __restrict__ Z,
                                                   const float* __restrict__ lamtab,
                                                   const float* __restrict__ E,
                                                   const float* __restrict__ Ct,
                                                   float* __restrict__ P) {
  const int c = blockIdx.x, b = blockIdx.y;
  const int t = threadIdx.x;
  __shared__ short bu[64][128];       // 16 KB (Bu_re|Bu_im for the chunk)
  __shared__ float xs_re[64][65];     // +1 pad
  __shared__ float xs_im[64][65];
  __shared__ float pm[16][64];
  const size_t zrow0 = (size_t)(b * L_ + c * CS) * WN;
  #pragma unroll
  for (int i = 0; i < 4; ++i) {
    int idx = t + 256 * i;
    int l = idx >> 4, part = idx & 15;
    *(short8*)&bu[l][part * 8] = *(const short8*)(Z + zrow0 + (size_t)l * WN + part * 8);
  }
  __syncthreads();
  if (t < 64) {
    const int h = t;
    const float lr = lamtab[h], li = lamtab[64 + h];
    const float Lr = lamtab[128 + h], Li = lamtab[192 + h];
    float cr = 0.f, ci = 0.f;
    const float* Eb = E + (size_t)b * NC * 128;
    for (int cp = 0; cp < c; ++cp) {         // carry = lam64*carry + E[cp]
      float er = Eb[cp * 128 + h], ei = Eb[cp * 128 + 64 + h];
      float nr = Lr * cr - Li * ci + er;
      ci = Lr * ci + Li * cr + ei;
      cr = nr;
    }
    float sr = cr, si = ci;
    for (int s = 0; s < 64; ++s) {
      float br = bf2f(bu[s][h]), bi = bf2f(bu[s][64 + h]);
      float nr = lr * sr - li * si + br;
      si = lr * si + li * sr + bi;
      sr = nr;
      xs_re[s][h] = sr; xs_im[s][h] = si;
    }
  }
  __syncthreads();
  const int to = t & 15, tl = t >> 4;
  const int o0 = to * 4, l0 = tl * 4;
  float y[4][4];
  #pragma unroll
  for (int i = 0; i < 4; ++i)
    #pragma unroll
    for (int j = 0; j < 4; ++j) y[i][j] = 0.f;
  for (int h = 0; h < 64; ++h) {
    f32x4 cre = *(const f32x4*)(Ct + h * 64 + o0);
    f32x4 cim = *(const f32x4*)(Ct + 4096 + h * 64 + o0);
    float xr[4], xi[4];
    #pragma unroll
    for (int i = 0; i < 4; ++i) { xr[i] = xs_re[l0 + i][h]; xi[i] = xs_im[l0 + i][h]; }
    #pragma unroll
    for (int i = 0; i < 4; ++i)
      #pragma unroll
      for (int j = 0; j < 4; ++j)
        y[i][j] += xr[i] * cre[j] + xi[i] * cim[j];
  }
  float mo[4] = {-3.4e38f, -3.4e38f, -3.4e38f, -3.4e38f};
  #pragma unroll
  for (int i = 0; i < 4; ++i)
    #pragma unroll
    for (int j = 0; j < 4; ++j) {
      float du = bf2f(Z[zrow0 + (size_t)(l0 + i) * WN + 128 + o0 + j]);
      float v = y[i][j] + du;
      mo[j] = fmaxf(mo[j], v);
    }
  #pragma unroll
  for (int j = 0; j < 4; ++j) pm[tl][o0 + j] = mo[j];
  __syncthreads();
  if (t < 64) {
    float mm = -3.4e38f;
    #pragma unroll
    for (int g = 0; g < 16; ++g) mm = fmaxf(mm, pm[g][t]);
    P[((size_t)b * NC + c) * 64 + t] = mm;
  }
}

// ---------------- K5: max over chunks ----------------
__global__ void k5_reduce(const float* __restrict__ P, float* __restrict__ out) {
  int idx = blockIdx.x * 256 + threadIdx.x;   // = b*64 + o
  int b = idx >> 6, o = idx & 63;
  float m = -3.4e38f;
  for (int c = 0; c < NC; ++c) m = fmaxf(m, P[((size_t)b * NC + c) * 64 + o]);
  out[idx] = m;
}

extern "C" void kernel_launch(void* const* d_in, const int* in_sizes, int n_in,
                              void* d_out, int out_size, void* d_ws, size_t ws_size,
                              hipStream_t stream) {
  const float* X         = (const float*)d_in[0];
  const float* nu_log    = (const float*)d_in[1];
  const float* theta_log = (const float*)d_in[2];
  const float* gamma_log = (const float*)d_in[3];
  const float* B_re      = (const float*)d_in[4];
  const float* B_im      = (const float*)d_in[5];
  const float* C_re      = (const float*)d_in[6];
  const float* C_im      = (const float*)d_in[7];
  const float* Dm        = (const float*)d_in[8];
  float* out = (float*)d_out;

  char* ws = (char*)d_ws;
  short* W      = (short*)ws;                                   // 147456 B
  float* lamtab = (float*)(ws + 147456);                        // 1024 B
  float* Ct     = (float*)(ws + 148480);                        // 32768 B
  short* Z      = (short*)(ws + 181248);                        // 25165824 B
  float* E      = (float*)(ws + 181248 + 25165824);             // 1048576 B
  float* P      = (float*)(ws + 181248 + 25165824 + 1048576);   // 262144 B

  k0_prep<<<64, 256, 0, stream>>>(nu_log, theta_log, gamma_log, B_re, B_im,
                                  C_re, C_im, Dm, W, lamtab, Ct);
  k1_gemm<<<1024, 256, 0, stream>>>(X, W, Z);
  dim3 g2(NC, B_);
  k2_chunkE<<<g2, 256, 0, stream>>>(Z, lamtab, E);
  k4_scanproj<<<g2, 256, 0, stream>>>(Z, lamtab, E, Ct, P);
  k5_reduce<<<8, 256, 0, stream>>>(P, out);
}

// Round 2
// 128.697 us; speedup vs baseline: 1.0606x; 1.0606x over previous
//
#include <hip/hip_runtime.h>
#include <hip/hip_bf16.h>

#define B_   32
#define L_   2048
#define DIN  384
#define DH   64
#define DOUT 64
#define CS   32      // chunk length
#define NC   64      // chunks per sequence
#define WN   192     // combined weight rows: [Bu_re | Bu_im | Du]

typedef __attribute__((ext_vector_type(8)))  short short8;
typedef __attribute__((ext_vector_type(4)))  float f32x4;
typedef __attribute__((ext_vector_type(16))) float f32x16;

__device__ __forceinline__ float bf2f(short s) {
  union { unsigned u; float f; } cv;
  cv.u = ((unsigned)(unsigned short)s) << 16;
  return cv.f;
}
__device__ __forceinline__ short f2bf(float f) {
  __hip_bfloat16 h = __float2bfloat16(f);   // RNE; compiler can pack to v_cvt_pk_bf16_f32
  union { __hip_bfloat16 h; short s; } cv; cv.h = h;
  return cv.s;
}

// ---------------- K0: weights / lambda / Ct prep ----------------
__global__ void k0_prep(const float* __restrict__ nu_log, const float* __restrict__ theta_log,
                        const float* __restrict__ gamma_log,
                        const float* __restrict__ B_re, const float* __restrict__ B_im,
                        const float* __restrict__ C_re, const float* __restrict__ C_im,
                        const float* __restrict__ Dm,
                        short* __restrict__ W, float* __restrict__ lamtab,
                        float* __restrict__ Ct) {
  int tid = blockIdx.x * 256 + threadIdx.x;
  for (int idx = tid; idx < WN * DIN; idx += gridDim.x * 256) {
    int n = idx / DIN, k = idx - n * DIN;
    float v;
    if (n < 64)       v = B_re[n * DIN + k] * expf(gamma_log[n]);
    else if (n < 128) v = B_im[(n - 64) * DIN + k] * expf(gamma_log[n - 64]);
    else              v = Dm[(n - 128) * DIN + k];
    W[idx] = f2bf(v);
  }
  // Ct[h][o] = C_re[o][h] ; Ct[4096 + h*64 + o] = -C_im[o][h]
  for (int idx = tid; idx < DH * DOUT; idx += gridDim.x * 256) {
    int h = idx / DOUT, o = idx - h * DOUT;
    Ct[idx] = C_re[o * DH + h];
    Ct[DH * DOUT + idx] = -C_im[o * DH + h];
  }
  if (blockIdx.x == 0 && threadIdx.x < 64) {
    int h = threadIdx.x;
    float nu = expf(nu_log[h]);
    float th = expf(theta_log[h]);
    float rr = expf(-nu);
    float lr = rr * cosf(th), li = rr * sinf(th);
    float ar = lr, ai = li;
    #pragma unroll
    for (int q = 0; q < 5; ++q) { float nr = ar * ar - ai * ai; ai = 2.f * ar * ai; ar = nr; }
    lamtab[h] = lr; lamtab[64 + h] = li;        // lambda
    lamtab[128 + h] = ar; lamtab[192 + h] = ai; // lambda^32
  }
}

// ---- K1: Z[65536][192] = X @ W^T (32x32x16 MFMA) + in-register chunk scan ----
// Each wave owns one 32-row chunk. After the K-loop it scans Bu (cols 0..127)
// in fp32 registers, stores LOCAL scan prefixes to Z, and emits the chunk
// end-state E (fp32). Du columns (128..191) stored unscanned.
__global__ __launch_bounds__(256, 2) void k1_gemm_scan(const float* __restrict__ X,
                                                       const short* __restrict__ W,
                                                       const float* __restrict__ lamtab,
                                                       short* __restrict__ Z,
                                                       float* __restrict__ E) {
  const int wave = threadIdx.x >> 6, lane = threadIdx.x & 63;
  const int c = lane & 31, khalf = lane >> 5;
  const int m0 = blockIdx.x * 128 + wave * 32;          // 32 rows = one chunk
  const int gchunk = blockIdx.x * 4 + wave;             // global chunk index

  f32x16 acc[6];
  #pragma unroll
  for (int i = 0; i < 6; ++i)
    #pragma unroll
    for (int j = 0; j < 16; ++j) acc[i][j] = 0.f;

  const float* xp = X + (size_t)(m0 + c) * DIN + khalf * 8;
  const short* wp = W + (size_t)c * DIN + khalf * 8;

  f32x4 a0 = *(const f32x4*)(xp);
  f32x4 a1 = *(const f32x4*)(xp + 4);
  short8 bcur[6];
  #pragma unroll
  for (int nt = 0; nt < 6; ++nt) bcur[nt] = *(const short8*)(wp + nt * 32 * DIN);

  #pragma unroll
  for (int ks = 0; ks < 24; ++ks) {
    short8 af;
    #pragma unroll
    for (int i = 0; i < 4; ++i) { af[i] = f2bf(a0[i]); af[4 + i] = f2bf(a1[i]); }
    short8 bold[6];
    #pragma unroll
    for (int nt = 0; nt < 6; ++nt) bold[nt] = bcur[nt];
    if (ks < 23) {
      a0 = *(const f32x4*)(xp + (ks + 1) * 16);
      a1 = *(const f32x4*)(xp + (ks + 1) * 16 + 4);
      #pragma unroll
      for (int nt = 0; nt < 6; ++nt)
        bcur[nt] = *(const short8*)(wp + nt * 32 * DIN + (ks + 1) * 16);
    }
    #pragma unroll
    for (int nt = 0; nt < 6; ++nt)
      acc[nt] = __builtin_amdgcn_mfma_f32_32x32x16_bf16(af, bold[nt], acc[nt], 0, 0, 0);
  }

  // ---- in-register local scan over the 32 rows, h1 = c (acc0/acc2), h2 = 32+c (acc1/acc3)
  const float lr1 = lamtab[c],      li1 = lamtab[64 + c];
  const float lr2 = lamtab[32 + c], li2 = lamtab[96 + c];
  float sr1 = 0.f, si1 = 0.f, sr2 = 0.f, si2 = 0.f;
  // row of acc element reg (this lane) = (reg&3) + 8*(reg>>2) + 4*khalf
  #pragma unroll
  for (int g = 0; g < 8; ++g) {
    const int active = (g & 1);
    if (khalf == active) {
      #pragma unroll
      for (int j = 0; j < 4; ++j) {
        const int r = 4 * (g >> 1) + j;
        float nr1 = lr1 * sr1 - li1 * si1 + acc[0][r];
        si1 = lr1 * si1 + li1 * sr1 + acc[2][r];
        sr1 = nr1;
        acc[0][r] = sr1; acc[2][r] = si1;
        float nr2 = lr2 * sr2 - li2 * si2 + acc[1][r];
        si2 = lr2 * si2 + li2 * sr2 + acc[3][r];
        sr2 = nr2;
        acc[1][r] = sr2; acc[3][r] = si2;
      }
    }
    float tr1 = __shfl_xor(sr1, 32), ti1 = __shfl_xor(si1, 32);
    float tr2 = __shfl_xor(sr2, 32), ti2 = __shfl_xor(si2, 32);
    if (khalf != active) { sr1 = tr1; si1 = ti1; sr2 = tr2; si2 = ti2; }
  }

  // ---- store Z (bf16): local prefixes for cols 0..127, raw Du for 128..191
  #pragma unroll
  for (int nt = 0; nt < 6; ++nt) {
    #pragma unroll
    for (int reg = 0; reg < 16; ++reg) {
      const int row = (reg & 3) + 8 * (reg >> 2) + 4 * khalf;
      Z[(size_t)(m0 + row) * WN + nt * 32 + c] = f2bf(acc[nt][reg]);
    }
  }
  // ---- store chunk end-state E (both halves hold the final state after g=7)
  if (khalf == 0) {
    float* Ep = E + (size_t)gchunk * 128;
    Ep[c] = sr1;       Ep[64 + c] = si1;
    Ep[32 + c] = sr2;  Ep[96 + c] = si2;
  }
}

// ---------------- K4: carry + correction + C-proj + Du + chunk max ----------------
__global__ __launch_bounds__(256) void k4_scanproj(const short* __restrict__ Z,
                                                   const float* __restrict__ lamtab,
                                                   const float* __restrict__ E,
                                                   const float* __restrict__ Ct,
                                                   float* __restrict__ P) {
  const int c = blockIdx.x, b = blockIdx.y;
  const int t = threadIdx.x;
  __shared__ short loc[CS][128];       // 8 KB: local scan prefixes (re|im)
  __shared__ float xs_re[CS][65];
  __shared__ float xs_im[CS][65];
  __shared__ float pm[16][64];
  const size_t zrow0 = (size_t)(b * NC + c) * CS * WN;

  #pragma unroll
  for (int i = 0; i < 2; ++i) {
    int idx = t + 256 * i;             // 512 short8 pieces
    int l = idx >> 4, p = idx & 15;
    *(short8*)&loc[l][p * 8] = *(const short8*)(Z + zrow0 + (size_t)l * WN + p * 8);
  }
  __syncthreads();

  if (t < 64) {
    const int h = t;
    const float Lr = lamtab[128 + h], Li = lamtab[192 + h];   // lambda^32
    const float lr = lamtab[h],       li = lamtab[64 + h];
    float cr = 0.f, ci = 0.f;
    const float* Eb = E + (size_t)b * NC * 128;
    for (int cp = 0; cp < c; ++cp) {
      float er = Eb[cp * 128 + h], ei = Eb[cp * 128 + 64 + h];
      float nr = Lr * cr - Li * ci + er;
      ci = Lr * ci + Li * cr + ei;
      cr = nr;
    }
    float wr = cr, wi = ci;
    for (int l = 0; l < CS; ++l) {
      float nr = lr * wr - li * wi;
      wi = lr * wi + li * wr;
      wr = nr;
      xs_re[l][h] = bf2f(loc[l][h])      + wr;
      xs_im[l][h] = bf2f(loc[l][64 + h]) + wi;
    }
  }
  __syncthreads();

  const int to = t & 15, tl = t >> 4;
  const int o0 = to * 4, l0 = tl * 2;
  float y[2][4];
  #pragma unroll
  for (int i = 0; i < 2; ++i)
    #pragma unroll
    for (int j = 0; j < 4; ++j) y[i][j] = 0.f;
  for (int h = 0; h < 64; ++h) {
    f32x4 cre = *(const f32x4*)(Ct + h * 64 + o0);
    f32x4 cim = *(const f32x4*)(Ct + 4096 + h * 64 + o0);
    float xr[2], xi[2];
    #pragma unroll
    for (int i = 0; i < 2; ++i) { xr[i] = xs_re[l0 + i][h]; xi[i] = xs_im[l0 + i][h]; }
    #pragma unroll
    for (int i = 0; i < 2; ++i)
      #pragma unroll
      for (int j = 0; j < 4; ++j)
        y[i][j] += xr[i] * cre[j] + xi[i] * cim[j];
  }
  float mo[4] = {-3.4e38f, -3.4e38f, -3.4e38f, -3.4e38f};
  #pragma unroll
  for (int i = 0; i < 2; ++i)
    #pragma unroll
    for (int j = 0; j < 4; ++j) {
      float du = bf2f(Z[zrow0 + (size_t)(l0 + i) * WN + 128 + o0 + j]);
      mo[j] = fmaxf(mo[j], y[i][j] + du);
    }
  #pragma unroll
  for (int j = 0; j < 4; ++j) pm[tl][o0 + j] = mo[j];
  __syncthreads();
  if (t < 64) {
    float mm = -3.4e38f;
    #pragma unroll
    for (int g = 0; g < 16; ++g) mm = fmaxf(mm, pm[g][t]);
    P[((size_t)b * NC + c) * 64 + t] = mm;
  }
}

// ---------------- K5: max over chunks ----------------
__global__ void k5_reduce(const float* __restrict__ P, float* __restrict__ out) {
  int idx = blockIdx.x * 256 + threadIdx.x;   // = b*64 + o
  int b = idx >> 6, o = idx & 63;
  float m = -3.4e38f;
  for (int c = 0; c < NC; ++c) m = fmaxf(m, P[((size_t)b * NC + c) * 64 + o]);
  out[idx] = m;
}

extern "C" void kernel_launch(void* const* d_in, const int* in_sizes, int n_in,
                              void* d_out, int out_size, void* d_ws, size_t ws_size,
                              hipStream_t stream) {
  const float* X         = (const float*)d_in[0];
  const float* nu_log    = (const float*)d_in[1];
  const float* theta_log = (const float*)d_in[2];
  const float* gamma_log = (const float*)d_in[3];
  const float* B_re      = (const float*)d_in[4];
  const float* B_im      = (const float*)d_in[5];
  const float* C_re      = (const float*)d_in[6];
  const float* C_im      = (const float*)d_in[7];
  const float* Dm        = (const float*)d_in[8];
  float* out = (float*)d_out;

  char* ws = (char*)d_ws;
  short* W      = (short*)ws;                                   // 147456 B
  float* lamtab = (float*)(ws + 147456);                        // 1024 B
  float* Ct     = (float*)(ws + 148480);                        // 32768 B
  short* Z      = (short*)(ws + 181248);                        // 25165824 B
  float* E      = (float*)(ws + 181248 + 25165824);             // 1048576 B
  float* P      = (float*)(ws + 181248 + 25165824 + 1048576);   // 524288 B

  k0_prep<<<64, 256, 0, stream>>>(nu_log, theta_log, gamma_log, B_re, B_im,
                                  C_re, C_im, Dm, W, lamtab, Ct);
  k1_gemm_scan<<<512, 256, 0, stream>>>(X, W, lamtab, Z, E);
  dim3 g2(NC, B_);
  k4_scanproj<<<g2, 256, 0, stream>>>(Z, lamtab, E, Ct, P);
  k5_reduce<<<8, 256, 0, stream>>>(P, out);
}

// Round 3
// 94.708 us; speedup vs baseline: 1.4412x; 1.3589x over previous
//
#include <hip/hip_runtime.h>
#include <hip/hip_bf16.h>

#define B_   32
#define L_   2048
#define DIN  384
#define DH   64
#define DOUT 64
#define CS   32      // chunk length
#define NC   64      // chunks per sequence
#define WN   192     // combined weight rows: [Bu_re | Bu_im | Du]

typedef __attribute__((ext_vector_type(8)))  short short8;
typedef __attribute__((ext_vector_type(4)))  float f32x4;
typedef __attribute__((ext_vector_type(16))) float f32x16;

__device__ __forceinline__ float bf2f(short s) {
  union { unsigned u; float f; } cv;
  cv.u = ((unsigned)(unsigned short)s) << 16;
  return cv.f;
}
__device__ __forceinline__ short f2bf(float f) {
  __hip_bfloat16 h = __float2bfloat16(f);
  union { __hip_bfloat16 h; short s; } cv; cv.h = h;
  return cv.s;
}

// ---------------- K0: pack Wp (B-frag order), Ctp (proj B-frag order), lamtab ----
__global__ void k0_prep(const float* __restrict__ nu_log, const float* __restrict__ theta_log,
                        const float* __restrict__ gamma_log,
                        const float* __restrict__ B_re, const float* __restrict__ B_im,
                        const float* __restrict__ C_re, const float* __restrict__ C_im,
                        const float* __restrict__ Dm,
                        short* __restrict__ Wp, short* __restrict__ Ctp,
                        float* __restrict__ lamtab) {
  int tid = blockIdx.x * 256 + threadIdx.x;
  // Wp[((nt*24+ks)*64+l)*8+j] = W[nt*32+(l&31)][ks*16+(l>>5)*8+j]
  for (int q = tid; q < 6 * 24 * 64; q += gridDim.x * 256) {
    int l = q & 63, ks = (q >> 6) % 24, nt = q / (24 * 64);
    int n = nt * 32 + (l & 31);
    int k0 = ks * 16 + ((l >> 5) << 3);
    short8 v;
    #pragma unroll
    for (int j = 0; j < 8; ++j) {
      int k = k0 + j;
      float x;
      if (n < 64)       x = B_re[n * DIN + k] * expf(gamma_log[n]);
      else if (n < 128) x = B_im[(n - 64) * DIN + k] * expf(gamma_log[n - 64]);
      else              x = Dm[(n - 128) * DIN + k];
      v[j] = f2bf(x);
    }
    *(short8*)(Wp + (size_t)q * 8) = v;
  }
  // Ctp[((nt2*8+ks2)*64+l)*8+j]: B[k][o], k<64 -> C_re[o][k], k>=64 -> -C_im[o][k-64]
  for (int q = tid; q < 2 * 8 * 64; q += gridDim.x * 256) {
    int l = q & 63, ks2 = (q >> 6) & 7, nt2 = q >> 9;
    int o = nt2 * 32 + (l & 31);
    int kk0 = ks2 * 16 + ((l >> 5) << 3);
    short8 v;
    #pragma unroll
    for (int j = 0; j < 8; ++j) {
      int k = kk0 + j;
      float x = (k < 64) ? C_re[o * DH + k] : -C_im[o * DH + (k - 64)];
      v[j] = f2bf(x);
    }
    *(short8*)(Ctp + (size_t)q * 8) = v;
  }
  if (blockIdx.x == 0 && threadIdx.x < 64) {
    int h = threadIdx.x;
    float nu = expf(nu_log[h]);
    float th = expf(theta_log[h]);
    float rr = expf(-nu);
    float lr = rr * cosf(th), li = rr * sinf(th);
    float ar = lr, ai = li;
    #pragma unroll
    for (int q = 0; q < 5; ++q) { float nr = ar * ar - ai * ai; ai = 2.f * ar * ai; ar = nr; }
    lamtab[h] = lr; lamtab[64 + h] = li;        // lambda
    lamtab[128 + h] = ar; lamtab[192 + h] = ai; // lambda^32
  }
}

// ---- K1: LDS-staged GEMM (32x32x16 MFMA) + in-register chunk scan ----
__global__ __launch_bounds__(128, 2) void k1_gemm_scan(const float* __restrict__ X,
                                                       const short* __restrict__ Wp,
                                                       const float* __restrict__ lamtab,
                                                       short* __restrict__ Z,
                                                       float* __restrict__ E) {
  __shared__ short Xs[64 * 384];                 // 48 KB, XOR-swizzled on 8-elem units
  const int t = threadIdx.x, w = t >> 6, lane = t & 63;
  const int m0 = blockIdx.x * 64;

  // ---- stage X tile: fp32 -> bf16 -> swizzled LDS (coalesced global reads)
  #pragma unroll
  for (int it = 0; it < 24; ++it) {
    int q8 = it * 128 + t;                       // 8-elem unit id, 0..3071
    int r = q8 / 48, u = q8 - r * 48;
    const float* src = X + (size_t)(m0 + r) * DIN + u * 8;
    f32x4 a0 = *(const f32x4*)src;
    f32x4 a1 = *(const f32x4*)(src + 4);
    short8 v;
    #pragma unroll
    for (int i = 0; i < 4; ++i) { v[i] = f2bf(a0[i]); v[4 + i] = f2bf(a1[i]); }
    int up = (u & ~7) | ((u ^ r) & 7);
    *(short8*)&Xs[r * 384 + up * 8] = v;
  }
  __syncthreads();

  const int c = lane & 31, kh = lane >> 5;
  const int rr = w * 32 + c;                     // row within tile (= chunk row)
  f32x16 acc[6];
  #pragma unroll
  for (int i = 0; i < 6; ++i)
    #pragma unroll
    for (int j = 0; j < 16; ++j) acc[i][j] = 0.f;

  const short* wpB = Wp + (size_t)lane * 8;
  short8 breg[2][6];
  #pragma unroll
  for (int nt = 0; nt < 6; ++nt) breg[0][nt] = *(const short8*)(wpB + (nt * 24 + 0) * 512);
  #pragma unroll
  for (int nt = 0; nt < 6; ++nt) breg[1][nt] = *(const short8*)(wpB + (nt * 24 + 1) * 512);

  #pragma unroll
  for (int ks = 0; ks < 24; ++ks) {
    int u = ks * 2 + kh;
    int up = (u & ~7) | ((u ^ rr) & 7);
    short8 af = *(const short8*)&Xs[rr * 384 + up * 8];
    short8 bv[6];
    #pragma unroll
    for (int nt = 0; nt < 6; ++nt) bv[nt] = breg[ks & 1][nt];
    if (ks < 22) {
      #pragma unroll
      for (int nt = 0; nt < 6; ++nt)
        breg[ks & 1][nt] = *(const short8*)(wpB + (nt * 24 + ks + 2) * 512);
    }
    #pragma unroll
    for (int nt = 0; nt < 6; ++nt)
      acc[nt] = __builtin_amdgcn_mfma_f32_32x32x16_bf16(af, bv[nt], acc[nt], 0, 0, 0);
  }

  // ---- in-register local scan over 32 rows; h1=c (acc0/acc2), h2=32+c (acc1/acc3)
  const float lr1 = lamtab[c],      li1 = lamtab[64 + c];
  const float lr2 = lamtab[32 + c], li2 = lamtab[96 + c];
  float sr1 = 0.f, si1 = 0.f, sr2 = 0.f, si2 = 0.f;
  #pragma unroll
  for (int g = 0; g < 8; ++g) {
    const int active = (g & 1);
    if (kh == active) {
      #pragma unroll
      for (int j = 0; j < 4; ++j) {
        const int r = 4 * (g >> 1) + j;
        float nr1 = lr1 * sr1 - li1 * si1 + acc[0][r];
        si1 = lr1 * si1 + li1 * sr1 + acc[2][r];
        sr1 = nr1;
        acc[0][r] = sr1; acc[2][r] = si1;
        float nr2 = lr2 * sr2 - li2 * si2 + acc[1][r];
        si2 = lr2 * si2 + li2 * sr2 + acc[3][r];
        sr2 = nr2;
        acc[1][r] = sr2; acc[3][r] = si2;
      }
    }
    float tr1 = __shfl_xor(sr1, 32), ti1 = __shfl_xor(si1, 32);
    float tr2 = __shfl_xor(sr2, 32), ti2 = __shfl_xor(si2, 32);
    if (kh != active) { sr1 = tr1; si1 = ti1; sr2 = tr2; si2 = ti2; }
  }

  // ---- store Z (bf16): local prefixes (cols 0..127) + raw Du (128..191)
  const int mrow = m0 + w * 32;
  #pragma unroll
  for (int nt = 0; nt < 6; ++nt) {
    #pragma unroll
    for (int reg = 0; reg < 16; ++reg) {
      const int row = (reg & 3) + 8 * (reg >> 2) + 4 * kh;
      Z[(size_t)(mrow + row) * WN + nt * 32 + c] = f2bf(acc[nt][reg]);
    }
  }
  if (kh == 0) {
    float* Ep = E + (size_t)(blockIdx.x * 2 + w) * 128;
    Ep[c] = sr1;       Ep[64 + c] = si1;
    Ep[32 + c] = sr2;  Ep[96 + c] = si2;
  }
}

// ---- K4: carry + correction + MFMA projection + Du + chunk max ----
__global__ __launch_bounds__(256, 2) void k4_scanproj(const short* __restrict__ Z,
                                                      const float* __restrict__ lamtab,
                                                      const float* __restrict__ E,
                                                      const short* __restrict__ Ctp,
                                                      float* __restrict__ P) {
  const int t = threadIdx.x, w = t >> 6, lane = t & 63;
  const int b = blockIdx.x >> 4, cg = blockIdx.x & 15;
  const int c = cg * 4 + w;                      // this wave's chunk
  __shared__ short Zs[4][CS * WN];               // 48 KB
  __shared__ short xsA[4][CS * 128];             // 32 KB, swizzled A-frag layout

  const size_t zbase = (size_t)(b * L_ + cg * 128) * WN;   // 4 consecutive chunks
  #pragma unroll
  for (int it = 0; it < 12; ++it) {
    int q = it * 256 + t;                        // short8 units, 0..3071
    ((short8*)Zs)[q] = *(const short8*)(Z + zbase + (size_t)q * 8);
  }
  __syncthreads();

  // carry over previous chunks (lane = h)
  const int h = lane;
  const float Lr = lamtab[128 + h], Li = lamtab[192 + h];
  const float lr = lamtab[h],       li = lamtab[64 + h];
  float cr = 0.f, ci = 0.f;
  const float* Eb = E + (size_t)b * NC * 128;
  for (int cp = 0; cp < c; ++cp) {
    float er = Eb[cp * 128 + h], ei = Eb[cp * 128 + 64 + h];
    float nr = Lr * cr - Li * ci + er;
    ci = Lr * ci + Li * cr + ei;
    cr = nr;
  }
  // correction: xs[l][h] = loc[l][h] + lam^{l+1} * carry ; write bf16 A-frag LDS
  {
    float wr2 = cr, wi2 = ci;
    short* xa = &xsA[w][0];
    const short* zs = &Zs[w][0];
    const int ure = h >> 3, uim = 8 + (h >> 3), ho = h & 7;
    #pragma unroll 4
    for (int l = 0; l < CS; ++l) {
      float nr = lr * wr2 - li * wi2;
      wi2 = lr * wi2 + li * wr2;
      wr2 = nr;
      float xr = bf2f(zs[l * WN + h])      + wr2;
      float xi = bf2f(zs[l * WN + 64 + h]) + wi2;
      int l7 = l & 7;
      xa[l * 128 + ((ure & ~7) | ((ure ^ l7) & 7)) * 8 + ho] = f2bf(xr);
      xa[l * 128 + ((uim & ~7) | ((uim ^ l7) & 7)) * 8 + ho] = f2bf(xi);
    }
  }
  __syncthreads();

  // MFMA projection: y(32x64) = [xs_re|xs_im](32x128) @ Ctp(128x64)
  const int cc = lane & 31, kh = lane >> 5;
  f32x16 y0, y1;
  #pragma unroll
  for (int j = 0; j < 16; ++j) { y0[j] = 0.f; y1[j] = 0.f; }
  #pragma unroll
  for (int ks = 0; ks < 8; ++ks) {
    int u = ks * 2 + kh;
    int up = (u & ~7) | ((u ^ (cc & 7)) & 7);
    short8 af = *(const short8*)&xsA[w][cc * 128 + up * 8];
    short8 b0 = *(const short8*)(Ctp + ((size_t)((0 * 8 + ks) * 64 + lane)) * 8);
    short8 b1 = *(const short8*)(Ctp + ((size_t)((1 * 8 + ks) * 64 + lane)) * 8);
    y0 = __builtin_amdgcn_mfma_f32_32x32x16_bf16(af, b0, y0, 0, 0, 0);
    y1 = __builtin_amdgcn_mfma_f32_32x32x16_bf16(af, b1, y1, 0, 0, 0);
  }
  // Du add + max over rows
  float mv0 = -3.4e38f, mv1 = -3.4e38f;
  #pragma unroll
  for (int reg = 0; reg < 16; ++reg) {
    const int row = (reg & 3) + 8 * (reg >> 2) + 4 * kh;
    float d0 = bf2f(Zs[w][row * WN + 128 + cc]);
    float d1 = bf2f(Zs[w][row * WN + 160 + cc]);
    mv0 = fmaxf(mv0, y0[reg] + d0);
    mv1 = fmaxf(mv1, y1[reg] + d1);
  }
  mv0 = fmaxf(mv0, __shfl_xor(mv0, 32));
  mv1 = fmaxf(mv1, __shfl_xor(mv1, 32));
  if (kh == 0) {
    float* Pp = P + ((size_t)b * NC + c) * 64;
    Pp[cc] = mv0;
    Pp[32 + cc] = mv1;
  }
}

// ---------------- K5: max over chunks ----------------
__global__ void k5_reduce(const float* __restrict__ P, float* __restrict__ out) {
  int idx = blockIdx.x * 256 + threadIdx.x;      // = b*64 + o
  int b = idx >> 6, o = idx & 63;
  float m = -3.4e38f;
  for (int c = 0; c < NC; ++c) m = fmaxf(m, P[((size_t)b * NC + c) * 64 + o]);
  out[idx] = m;
}

extern "C" void kernel_launch(void* const* d_in, const int* in_sizes, int n_in,
                              void* d_out, int out_size, void* d_ws, size_t ws_size,
                              hipStream_t stream) {
  const float* X         = (const float*)d_in[0];
  const float* nu_log    = (const float*)d_in[1];
  const float* theta_log = (const float*)d_in[2];
  const float* gamma_log = (const float*)d_in[3];
  const float* B_re      = (const float*)d_in[4];
  const float* B_im      = (const float*)d_in[5];
  const float* C_re      = (const float*)d_in[6];
  const float* C_im      = (const float*)d_in[7];
  const float* Dm        = (const float*)d_in[8];
  float* out = (float*)d_out;

  char* ws = (char*)d_ws;
  short* Wp     = (short*)ws;                       // 147456 B
  short* Ctp    = (short*)(ws + 147456);            // 16384 B
  float* lamtab = (float*)(ws + 163840);            // 1024 B
  short* Z      = (short*)(ws + 165888);            // 25165824 B
  float* E      = (float*)(ws + 165888 + 25165824); // 1048576 B
  float* P      = (float*)(ws + 165888 + 25165824 + 1048576); // 524288 B

  k0_prep<<<64, 256, 0, stream>>>(nu_log, theta_log, gamma_log, B_re, B_im,
                                  C_re, C_im, Dm, Wp, Ctp, lamtab);
  k1_gemm_scan<<<1024, 128, 0, stream>>>(X, Wp, lamtab, Z, E);
  k4_scanproj<<<512, 256, 0, stream>>>(Z, lamtab, E, Ctp, P);
  k5_reduce<<<8, 256, 0, stream>>>(P, out);
}